// Round 1
// baseline (478.997 us; speedup 1.0000x reference)
//
#include <hip/hip_runtime.h>
#include <hip/hip_bf16.h>

// KNN Gaussian blur: out = blur(img[0]/max)*max == blur(img[0]) (blur is linear).
// Separable 25-tap Gaussian, sigma=4, replicate padding, C=3, H=W=4096, fp32.

#define IMG_W 4096
#define IMG_H 4096
#define N_CH  3
#define HALF  12
#define KSZ   25

#define TILE_W 104              // output tile width
#define TILE_H 64               // output tile height
#define COLS   (TILE_W + 2*HALF) // 128 intermediate columns
#define LDS_STRIDE (COLS + 1)   // pad to break bank alignment on horizontal reads
#define ROWS_IN (TILE_H/2 + 2*HALF) // 56 input rows per y-group strip

// Normalized Gaussian weights: exp(-0.5*(x/4)^2)/sum, x=-12..12
__device__ __constant__ float kW[KSZ] = {
    0.00110988f, 0.00227883f, 0.00438965f, 0.00794860f, 0.01352109f,
    0.02160664f, 0.03243540f, 0.04574124f, 0.06059730f, 0.07541456f,
    0.08816855f, 0.09683420f, 0.09990806f, 0.09683420f, 0.08816855f,
    0.07541456f, 0.06059730f, 0.04574124f, 0.03243540f, 0.02160664f,
    0.01352109f, 0.00794860f, 0.00438965f, 0.00227883f, 0.00110988f
};

__global__ __launch_bounds__(256)
void gauss_blur_fused(const float* __restrict__ img, float* __restrict__ out)
{
    __shared__ float inter[TILE_H * LDS_STRIDE]; // 64*129*4 = 33024 B

    const int tid = threadIdx.x;
    const int x0  = blockIdx.x * TILE_W;
    const int y0  = blockIdx.y * TILE_H;
    const int c   = blockIdx.z;

    const float* __restrict__ src = img + (size_t)c * IMG_W * IMG_H;
    float* __restrict__ dst       = out + (size_t)c * IMG_W * IMG_H;

    // ---------------- vertical pass (global -> LDS), register sliding window
    {
        const int colg = tid & (COLS - 1);   // 0..127
        const int grp  = tid >> 7;           // 0 or 1 (y half)
        int gx = x0 - HALF + colg;
        gx = gx < 0 ? 0 : (gx > IMG_W - 1 ? IMG_W - 1 : gx);
        const int ybase = y0 + grp * (TILE_H / 2);

        float r[ROWS_IN];
        #pragma unroll
        for (int i = 0; i < ROWS_IN; ++i) {
            int gy = ybase - HALF + i;
            gy = gy < 0 ? 0 : (gy > IMG_H - 1 ? IMG_H - 1 : gy);
            r[i] = src[(size_t)gy * IMG_W + gx];
        }

        #pragma unroll
        for (int i = 0; i < TILE_H / 2; ++i) {
            float acc = 0.f;
            #pragma unroll
            for (int k = 0; k < KSZ; ++k)
                acc += kW[k] * r[i + k];
            inter[(grp * (TILE_H / 2) + i) * LDS_STRIDE + colg] = acc;
        }
    }
    __syncthreads();

    // ---------------- horizontal pass (LDS -> global), 13-px register chunks
    // 64 rows * 8 chunks = 512 tasks, 2 per thread
    #pragma unroll
    for (int t = 0; t < 2; ++t) {
        const int task  = tid + t * 256;     // 0..511
        const int row   = task >> 3;         // 0..63
        const int chunk = task & 7;          // 0..7
        const int xl    = chunk * 13;        // local output x start

        float v[13 + 2 * HALF];              // 37 values
        #pragma unroll
        for (int i = 0; i < 13 + 2 * HALF; ++i)
            v[i] = inter[row * LDS_STRIDE + xl + i];

        const size_t base = (size_t)(y0 + row) * IMG_W;
        #pragma unroll
        for (int j = 0; j < 13; ++j) {
            float acc = 0.f;
            #pragma unroll
            for (int k = 0; k < KSZ; ++k)
                acc += kW[k] * v[j + k];
            const int gxo = x0 + xl + j;
            if (gxo < IMG_W)
                dst[base + gxo] = acc;
        }
    }
}

extern "C" void kernel_launch(void* const* d_in, const int* in_sizes, int n_in,
                              void* d_out, int out_size, void* d_ws, size_t ws_size,
                              hipStream_t stream)
{
    const float* img = (const float*)d_in[0];
    float* out = (float*)d_out;

    dim3 grid((IMG_W + TILE_W - 1) / TILE_W,  // 40
              IMG_H / TILE_H,                 // 64
              N_CH);                          // 3
    dim3 block(256);
    gauss_blur_fused<<<grid, block, 0, stream>>>(img, out);
}